// Round 12
// baseline (315287.549 us; speedup 1.0000x reference)
//
#include <hip/hip_runtime.h>
#include <math.h>

#define VOCAB 32000
#define D_IN  256
#define D_H   32
#define B_SZ  16
#define S_LEN 512
#define NTOK  (B_SZ * S_LEN)   // 8192
#define SG    (S_LEN / 4)      // 128 step-groups
#define SGP   (SG + 1)         // padded (last group = zeros)

#define NWIN  256              // 32-token windows (16 batches x 16 chunks)
#define NV1   16               // sum vocab splits (2000 rows, 125 tiles)
#define VT1   (VOCAB / 16 / NV1)
#define NVO   8                // out vocab splits (4000 rows, 250 tiles)
#define VTO   (VOCAB / 16 / NVO)
#define NS_BLK 480
#define NO_BLK 480

typedef __bf16 bf16;
typedef __attribute__((ext_vector_type(8))) __bf16 bf16x8;
typedef __attribute__((ext_vector_type(4))) __bf16 bf16x4;
typedef __attribute__((ext_vector_type(4))) float f32x4;
typedef __attribute__((ext_vector_type(2))) float f32x2;

__device__ __forceinline__ float sigf(float x) {
    return 1.0f / (1.0f + __expf(-x));
}

__device__ __forceinline__ float tanhfast(float x) {
    float ax = fabsf(x);
    float e = __expf(-2.0f * ax);
    float r = (1.0f - e) / (1.0f + e);
    return copysignf(r, x);
}

__device__ __forceinline__ float dot4(float4 a, float4 b) {
    return a.x * b.x + a.y * b.y + a.z * b.z + a.w * b.w;
}

__device__ __forceinline__ float rl(float v, int j) {
    return __builtin_bit_cast(float, __builtin_amdgcn_readlane(__builtin_bit_cast(int, v), j));
}

__device__ __forceinline__ void xswap32(float a, bool convA, float& P, float& Q) {
    float x = a, y = a;
    asm volatile("v_permlane32_swap_b32 %0, %1" : "+v"(x), "+v"(y));
    P = convA ? y : x;
    Q = convA ? x : y;
}

// ---------------------------------------------------------------------------
__global__ __launch_bounds__(256) void k_cvt_w(
    const float* __restrict__ W, bf16* __restrict__ Whi, bf16* __restrict__ Wlo)
{
    const long i = ((long)blockIdx.x * 256 + threadIdx.x) * 4;
    float4 w = *(const float4*)(W + i);
    bf16 h0 = (bf16)w.x, h1 = (bf16)w.y, h2 = (bf16)w.z, h3 = (bf16)w.w;
    bf16 l0 = (bf16)(w.x - (float)h0), l1 = (bf16)(w.y - (float)h1);
    bf16 l2 = (bf16)(w.z - (float)h2), l3 = (bf16)(w.w - (float)h3);
    bf16x4 hv = {h0, h1, h2, h3}, lv = {l0, l1, l2, l3};
    *(bf16x4*)(Whi + i) = hv;
    *(bf16x4*)(Wlo + i) = lv;
}

__global__ __launch_bounds__(256) void k_g1pad(float4* __restrict__ G1p)
{
    const int idx = blockIdx.x * 256 + threadIdx.x;
    G1p[((long)(idx >> 7) * 128 + (idx & 127)) * SGP + SG] = (float4){0.f, 0.f, 0.f, 0.f};
}

__global__ __launch_bounds__(256) void k_zero(int* __restrict__ flags)
{
    for (int i = threadIdx.x; i < 544; i += 256) flags[i] = 0;
}

// ---------------------------------------------------------------------------
__global__ __launch_bounds__(128) void k_embed_gates(
    const int* __restrict__ x_ids, const float* __restrict__ emb,
    const float* __restrict__ W_ih1, const float* __restrict__ b_ih1,
    const float* __restrict__ b_hh1, float4* __restrict__ G1p)
{
    __shared__ float4 xs[4][64];
    const int tid = threadIdx.x;
    const int t0  = blockIdx.x * 4;
    const int r0  = tid >> 6, j = tid & 63;
    #pragma unroll
    for (int rr = 0; rr < 2; ++rr) {
        int r = rr * 2 + r0;
        long id = x_ids[t0 + r];
        xs[r][j] = ((const float4*)(emb + id * (long)D_IN))[j];
    }
    __syncthreads();

    const int g = tid;
    const float4* wrow = (const float4*)(W_ih1 + (long)g * D_IN);
    const float bias = b_ih1[g] + b_hh1[g];
    float a0 = bias, a1 = bias, a2 = bias, a3 = bias;
    #pragma unroll 8
    for (int jj = 0; jj < 64; ++jj) {
        float4 w = wrow[jj];
        a0 += dot4(w, xs[0][jj]);
        a1 += dot4(w, xs[1][jj]);
        a2 += dot4(w, xs[2][jj]);
        a3 += dot4(w, xs[3][jj]);
    }
    const int b  = t0 >> 9;
    const int sg = (t0 & 511) >> 2;
    G1p[((long)b * 128 + g) * SGP + sg] = (float4){a0, a1, a2, a3};
}

// ---------------------------------------------------------------------------
// Fused pipeline kernel.
// blocks 0..15           : LSTM chain (wave 0 only), publishes prog[b] per 32 steps
// blocks 16..16+NS-1     : fc_sum waves (spin on prog), last wave/window does inv
// blocks 16+NS..         : fc_out waves (spin on fin)
// Capacity: __launch_bounds__(256,4) -> VGPR<=128 -> 4 blocks/CU -> 1024 >= 976 grid
// => all blocks co-resident, spins always satisfied.
// ---------------------------------------------------------------------------
__global__ __launch_bounds__(256, 4) void k_pipe(
    const float4* __restrict__ G1p,
    const float* __restrict__ W_hh1,
    const float* __restrict__ W_ih2, const float* __restrict__ W_hh2,
    const float* __restrict__ b_ih2, const float* __restrict__ b_hh2,
    bf16* __restrict__ Hhi, bf16* __restrict__ Hlo,
    const bf16* __restrict__ Whi, const bf16* __restrict__ Wlo,
    const float* __restrict__ b_fc,
    float* __restrict__ partial, float* __restrict__ inv_sum,
    float* __restrict__ out, int* __restrict__ flags)
{
    __shared__ alignas(16) float hring[32 * D_H];   // 4 KB (LSTM role only)
    int* prog = flags;          // [16]
    int* scnt = flags + 16;     // [256]
    int* fin  = flags + 272;    // [256]

    const int bid = blockIdx.x;

    if (bid < 16) {
        // ================= LSTM role =================
        if (threadIdx.x >= 64) return;
        const int l = threadIdx.x;
        const int b = bid;
        const int ga = l, gb = 64 + l;

        int px = l, py = l;
        asm volatile("v_permlane32_swap_b32 %0, %1" : "+v"(px), "+v"(py));
        const bool convA = (__builtin_amdgcn_readfirstlane(px) == 32);

        f32x2 w1[32], wi2[32], wh2[32];
        #pragma unroll
        for (int j = 0; j < 32; ++j) {
            w1[j]  = (f32x2){ W_hh1[ga * D_H + j], W_hh1[gb * D_H + j] };
            wi2[j] = (f32x2){ W_ih2[ga * D_H + j], W_ih2[gb * D_H + j] };
            wh2[j] = (f32x2){ W_hh2[ga * D_H + j], W_hh2[gb * D_H + j] };
        }
        const float bias2a = b_ih2[ga] + b_hh2[ga];
        const float bias2b = b_ih2[gb] + b_hh2[gb];

        const float4* rowA = G1p + ((long)b * 128 + ga) * SGP;
        const float4* rowB = G1p + ((long)b * 128 + gb) * SGP;
        float4 curA = rowA[0], curB = rowB[0];

        float h1v = 0.0f, h2v = 0.0f, c1 = 0.0f, c2 = 0.0f;
        bf16* ghi = Hhi + (long)b * S_LEN * D_H;
        bf16* glo = Hlo + (long)b * S_LEN * D_H;

        #pragma unroll 1
        for (int sg = 0; sg < SG; ++sg) {
            float4 nxtA = rowA[sg + 1];
            float4 nxtB = rowB[sg + 1];

            #pragma unroll
            for (int k = 0; k < 4; ++k) {
                const int s = sg * 4 + k;
                const float g1a = (k == 0) ? curA.x : (k == 1) ? curA.y
                                : (k == 2) ? curA.z : curA.w;
                const float g1b = (k == 0) ? curB.x : (k == 1) ? curB.y
                                : (k == 2) ? curB.z : curB.w;

                f32x2 R0 = {0.f,0.f}, R1 = {0.f,0.f}, R2 = {0.f,0.f}, R3 = {0.f,0.f};
                #pragma unroll
                for (int j = 0; j < 32; j += 4) {
                    R0 += wh2[j]     * rl(h2v, j);
                    R1 += wh2[j + 1] * rl(h2v, j + 1);
                    R2 += wh2[j + 2] * rl(h2v, j + 2);
                    R3 += wh2[j + 3] * rl(h2v, j + 3);
                }
                f32x2 A0 = {0.f,0.f}, A1 = {0.f,0.f}, A2 = {0.f,0.f}, A3 = {0.f,0.f};
                #pragma unroll
                for (int j = 0; j < 32; j += 4) {
                    A0 += w1[j]     * rl(h1v, j);
                    A1 += w1[j + 1] * rl(h1v, j + 1);
                    A2 += w1[j + 2] * rl(h1v, j + 2);
                    A3 += w1[j + 3] * rl(h1v, j + 3);
                }
                f32x2 As = (A0 + A1) + (A2 + A3);
                float accA = g1a + As.x;
                float accB = g1b + As.y;
                float aa = sigf(accA);
                float ab = (l < 32) ? tanhfast(accB) : sigf(accB);
                float iv, fv, gv, ov;
                xswap32(aa, convA, iv, fv);
                xswap32(ab, convA, gv, ov);
                c1 = fv * c1 + iv * gv;
                h1v = ov * tanhfast(c1);

                #pragma unroll
                for (int j = 0; j < 32; j += 4) {
                    R0 += wi2[j]     * rl(h1v, j);
                    R1 += wi2[j + 1] * rl(h1v, j + 1);
                    R2 += wi2[j + 2] * rl(h1v, j + 2);
                    R3 += wi2[j + 3] * rl(h1v, j + 3);
                }
                f32x2 Rs = (R0 + R1) + (R2 + R3);
                float a2 = bias2a + Rs.x;
                float b2 = bias2b + Rs.y;
                aa = sigf(a2);
                ab = (l < 32) ? tanhfast(b2) : sigf(b2);
                xswap32(aa, convA, iv, fv);
                xswap32(ab, convA, gv, ov);
                c2 = fv * c2 + iv * gv;
                h2v = ov * tanhfast(c2);

                if (l < 32) hring[(s & 31) * D_H + l] = h2v;
            }
            curA = nxtA; curB = nxtB;

            if ((sg & 7) == 7) {
                // flush 32-step chunk c = sg>>3 to global as bf16 hi/lo
                const int c = sg >> 3;
                const long base = (long)c * 32 * D_H;
                #pragma unroll
                for (int it = 0; it < 4; ++it) {
                    const int i = it * 256 + l * 4;
                    float4 v = *(const float4*)&hring[i];
                    bf16 h0 = (bf16)v.x, h1 = (bf16)v.y, h2 = (bf16)v.z, h3 = (bf16)v.w;
                    bf16x4 hv = {h0, h1, h2, h3};
                    bf16x4 lv = {(bf16)(v.x - (float)h0), (bf16)(v.y - (float)h1),
                                 (bf16)(v.z - (float)h2), (bf16)(v.w - (float)h3)};
                    *(bf16x4*)(ghi + base + i) = hv;
                    *(bf16x4*)(glo + base + i) = lv;
                }
                if (l == 0) {
                    __hip_atomic_store(prog + b, c + 1, __ATOMIC_RELEASE,
                                       __HIP_MEMORY_SCOPE_AGENT);
                }
            }
        }
        return;
    }

    // ================= fc roles =================
    const int fb   = bid - 16;
    const int wid  = threadIdx.x >> 6;
    const int lane = threadIdx.x & 63;
    const int lr   = lane & 15, lq = lane >> 4;
    const f32x4 z  = {0.f, 0.f, 0.f, 0.f};

    if (fb < NS_BLK) {
        // ---- fc_sum + inv ----
        const int slot = fb * 4 + wid;
        for (int it = slot; it < NWIN * NV1; it += NS_BLK * 4) {
            const int wo = it / NV1, nv = it % NV1;
            const int c = wo >> 4, bb = wo & 15;

            int pv;
            do {
                pv = __hip_atomic_load(prog + bb, __ATOMIC_ACQUIRE,
                                       __HIP_MEMORY_SCOPE_AGENT);
                if (pv > c) break;
                __builtin_amdgcn_s_sleep(8);
            } while (true);

            const long t0 = (long)bb * S_LEN + (long)c * 32;
            const long arow0 = (t0 + lr) * D_H + lq * 8;
            const long arow1 = arow0 + 16 * D_H;
            bf16x8 a0h = *(const bf16x8*)(Hhi + arow0);
            bf16x8 a0l = *(const bf16x8*)(Hlo + arow0);
            bf16x8 a1h = *(const bf16x8*)(Hhi + arow1);
            bf16x8 a1l = *(const bf16x8*)(Hlo + arow1);

            f32x4 acc0 = z, acc1 = z;
            int v0 = nv * (VOCAB / NV1);
            for (int tile = 0; tile < VT1; ++tile, v0 += 16) {
                const long brow = (long)(v0 + lr) * D_H + lq * 8;
                bf16x8 bh = *(const bf16x8*)(Whi + brow);
                bf16x8 bl = *(const bf16x8*)(Wlo + brow);
                float bias = b_fc[v0 + lr];
                f32x4 d0 = __builtin_amdgcn_mfma_f32_16x16x32_bf16(a0h, bh, z, 0, 0, 0);
                d0 = __builtin_amdgcn_mfma_f32_16x16x32_bf16(a0l, bh, d0, 0, 0, 0);
                d0 = __builtin_amdgcn_mfma_f32_16x16x32_bf16(a0h, bl, d0, 0, 0, 0);
                f32x4 d1 = __builtin_amdgcn_mfma_f32_16x16x32_bf16(a1h, bh, z, 0, 0, 0);
                d1 = __builtin_amdgcn_mfma_f32_16x16x32_bf16(a1l, bh, d1, 0, 0, 0);
                d1 = __builtin_amdgcn_mfma_f32_16x16x32_bf16(a1h, bl, d1, 0, 0, 0);
                #pragma unroll
                for (int r = 0; r < 4; ++r) {
                    acc0[r] += __expf(d0[r] + bias);
                    acc1[r] += __expf(d1[r] + bias);
                }
            }
            #pragma unroll
            for (int m = 1; m < 16; m <<= 1) {
                #pragma unroll
                for (int r = 0; r < 4; ++r) {
                    acc0[r] += __shfl_xor(acc0[r], m, 64);
                    acc1[r] += __shfl_xor(acc1[r], m, 64);
                }
            }
            if (lr == 0) {
                #pragma unroll
                for (int r = 0; r < 4; ++r) {
                    partial[(long)nv * NTOK + t0 + lq * 4 + r]      = acc0[r];
                    partial[(long)nv * NTOK + t0 + 16 + lq * 4 + r] = acc1[r];
                }
            }
            int prev = 0;
            if (lane == 0) {
                prev = __hip_atomic_fetch_add(scnt + wo, 1, __ATOMIC_ACQ_REL,
                                              __HIP_MEMORY_SCOPE_AGENT);
            }
            prev = __shfl(prev, 0, 64);
            if (prev == NV1 - 1) {
                if (lane < 32) {
                    const long t = t0 + lane;
                    float s = 0.0f;
                    #pragma unroll
                    for (int q = 0; q < NV1; ++q) s += partial[(long)q * NTOK + t];
                    inv_sum[t] = 1.0f / s;
                }
                if (lane == 0) {
                    __hip_atomic_store(fin + wo, 1, __ATOMIC_RELEASE,
                                       __HIP_MEMORY_SCOPE_AGENT);
                }
            }
        }
    } else {
        // ---- fc_out ----
        const int slot = (fb - NS_BLK) * 4 + wid;
        for (int it = slot; it < NWIN * NVO; it += NO_BLK * 4) {
            const int wo = it / NVO, nv = it % NVO;
            const int c = wo >> 4, bb = wo & 15;

            do {
                int fv = __hip_atomic_load(fin + wo, __ATOMIC_ACQUIRE,
                                           __HIP_MEMORY_SCOPE_AGENT);
                if (fv != 0) break;
                __builtin_amdgcn_s_sleep(8);
            } while (true);

            const long t0 = (long)bb * S_LEN + (long)c * 32;
            const long arow0 = (t0 + lr) * D_H + lq * 8;
            const long arow1 = arow0 + 16 * D_H;
            bf16x8 a0h = *(const bf16x8*)(Hhi + arow0);
            bf16x8 a0l = *(const bf16x8*)(Hlo + arow0);
            bf16x8 a1h = *(const bf16x8*)(Hhi + arow1);
            bf16x8 a1l = *(const bf16x8*)(Hlo + arow1);

            float inv0[4], inv1[4];
            #pragma unroll
            for (int r = 0; r < 4; ++r) {
                inv0[r] = inv_sum[t0 + lq * 4 + r];
                inv1[r] = inv_sum[t0 + 16 + lq * 4 + r];
            }

            int v0 = nv * (VOCAB / NVO);
            for (int tile = 0; tile < VTO; ++tile, v0 += 16) {
                const long brow = (long)(v0 + lr) * D_H + lq * 8;
                bf16x8 bh = *(const bf16x8*)(Whi + brow);
                bf16x8 bl = *(const bf16x8*)(Wlo + brow);
                float bias = b_fc[v0 + lr];
                f32x4 d0 = __builtin_amdgcn_mfma_f32_16x16x32_bf16(a0h, bh, z, 0, 0, 0);
                d0 = __builtin_amdgcn_mfma_f32_16x16x32_bf16(a0l, bh, d0, 0, 0, 0);
                d0 = __builtin_amdgcn_mfma_f32_16x16x32_bf16(a0h, bl, d0, 0, 0, 0);
                f32x4 d1 = __builtin_amdgcn_mfma_f32_16x16x32_bf16(a1h, bh, z, 0, 0, 0);
                d1 = __builtin_amdgcn_mfma_f32_16x16x32_bf16(a1l, bh, d1, 0, 0, 0);
                d1 = __builtin_amdgcn_mfma_f32_16x16x32_bf16(a1h, bl, d1, 0, 0, 0);
                const int vcol = v0 + lr;
                #pragma unroll
                for (int r = 0; r < 4; ++r) {
                    out[(t0 + lq * 4 + r) * VOCAB + vcol] =
                        __expf(d0[r] + bias) * inv0[r];
                    out[(t0 + 16 + lq * 4 + r) * VOCAB + vcol] =
                        __expf(d1[r] + bias) * inv1[r];
                }
            }
        }
    }
}

// ---------------------------------------------------------------------------
extern "C" void kernel_launch(void* const* d_in, const int* in_sizes, int n_in,
                              void* d_out, int out_size, void* d_ws, size_t ws_size,
                              hipStream_t stream)
{
    const int*   x_ids = (const int*)d_in[0];
    const float* emb   = (const float*)d_in[1];
    const float* W_ih1 = (const float*)d_in[2];
    const float* W_hh1 = (const float*)d_in[3];
    const float* b_ih1 = (const float*)d_in[4];
    const float* b_hh1 = (const float*)d_in[5];
    const float* W_ih2 = (const float*)d_in[6];
    const float* W_hh2 = (const float*)d_in[7];
    const float* b_ih2 = (const float*)d_in[8];
    const float* b_hh2 = (const float*)d_in[9];
    const float* W_fc  = (const float*)d_in[10];
    const float* b_fc  = (const float*)d_in[11];
    float* out = (float*)d_out;

    char* p = (char*)d_ws;
    float4* G1p    = (float4*)p;           p += (long)B_SZ * 128 * SGP * 16; // ~4.2 MB
    bf16* Hhi      = (bf16*)p;             p += (long)NTOK * D_H * 2;
    bf16* Hlo      = (bf16*)p;             p += (long)NTOK * D_H * 2;
    bf16* Whi      = (bf16*)p;             p += (long)VOCAB * D_H * 2;
    bf16* Wlo      = (bf16*)p;             p += (long)VOCAB * D_H * 2;
    float* partial = (float*)p;            p += (long)NV1 * NTOK * 4;
    float* inv_sum = (float*)p;            p += (long)NTOK * 4;
    int* flags     = (int*)p;              p += 544 * 4;

    k_cvt_w<<<VOCAB * D_H / (256 * 4), 256, 0, stream>>>(W_fc, Whi, Wlo);
    k_g1pad<<<8, 256, 0, stream>>>(G1p);
    k_zero<<<1, 256, 0, stream>>>(flags);
    k_embed_gates<<<NTOK / 4, 128, 0, stream>>>(x_ids, emb, W_ih1, b_ih1, b_hh1, G1p);
    k_pipe<<<16 + NS_BLK + NO_BLK, 256, 0, stream>>>(
        G1p, W_hh1, W_ih2, W_hh2, b_ih2, b_hh2,
        Hhi, Hlo, Whi, Wlo, b_fc, partial, inv_sum, out, flags);
}

// Round 13
// 1049.980 us; speedup vs baseline: 300.2797x; 300.2797x over previous
//
#include <hip/hip_runtime.h>
#include <math.h>

#define VOCAB 32000
#define D_IN  256
#define D_H   32
#define B_SZ  16
#define S_LEN 512
#define NTOK  (B_SZ * S_LEN)   // 8192
#define NV1   16               // vocab splits in sum pass
#define VT1   (VOCAB / 16 / NV1)   // 125 tiles of 16 rows
#define NV2   25               // vocab splits in out pass
#define VT2   (VOCAB / 16 / NV2)   // 80 tiles

typedef __bf16 bf16;
typedef __attribute__((ext_vector_type(8))) __bf16 bf16x8;
typedef __attribute__((ext_vector_type(4))) __bf16 bf16x4;
typedef __attribute__((ext_vector_type(4))) float f32x4;

__device__ __forceinline__ float sigf(float x) {
    return 1.0f / (1.0f + __expf(-x));
}

__device__ __forceinline__ float tanhfast(float x) {
    float ax = fabsf(x);
    float e = __expf(-2.0f * ax);
    float r = (1.0f - e) / (1.0f + e);
    return copysignf(r, x);
}

__device__ __forceinline__ float dot4(float4 a, float4 b) {
    return a.x * b.x + a.y * b.y + a.z * b.z + a.w * b.w;
}

// ---------------------------------------------------------------------------
// Convert W_fc (f32 [32000][32]) to bf16 hi/lo split arrays.
// ---------------------------------------------------------------------------
__global__ __launch_bounds__(256) void k_cvt_w(
    const float* __restrict__ W, bf16* __restrict__ Whi, bf16* __restrict__ Wlo)
{
    const long i = ((long)blockIdx.x * 256 + threadIdx.x) * 4;
    float4 w = *(const float4*)(W + i);
    bf16 h0 = (bf16)w.x, h1 = (bf16)w.y, h2 = (bf16)w.z, h3 = (bf16)w.w;
    bf16 l0 = (bf16)(w.x - (float)h0), l1 = (bf16)(w.y - (float)h1);
    bf16 l2 = (bf16)(w.z - (float)h2), l3 = (bf16)(w.w - (float)h3);
    bf16x4 hv = {h0, h1, h2, h3}, lv = {l0, l1, l2, l3};
    *(bf16x4*)(Whi + i) = hv;
    *(bf16x4*)(Wlo + i) = lv;
}

// ---------------------------------------------------------------------------
// Kernel A: input-side gates, packed into MFMA C/D-fragment order:
// G1d float index (((s*8 + w)*64 + lane)*4 + r) holds gate[b=lq*4+r][col=g]
// for lane = (b>>2)*16 + (g&15), w = g>>4.
// ---------------------------------------------------------------------------
__global__ __launch_bounds__(128) void k_embed_gates(
    const int* __restrict__ x_ids, const float* __restrict__ emb,
    const float* __restrict__ W_ih1, const float* __restrict__ b_ih1,
    const float* __restrict__ b_hh1, float* __restrict__ G1d)
{
    __shared__ float4 xs[4][64];
    const int tid = threadIdx.x;
    const int t0  = blockIdx.x * 4;          // 4 consecutive tokens, same batch
    const int r0  = tid >> 6, j = tid & 63;
    #pragma unroll
    for (int rr = 0; rr < 2; ++rr) {
        int r = rr * 2 + r0;
        long id = x_ids[t0 + r];
        xs[r][j] = ((const float4*)(emb + id * (long)D_IN))[j];
    }
    __syncthreads();

    const int g = tid;
    const float4* wrow = (const float4*)(W_ih1 + (long)g * D_IN);
    const float bias = b_ih1[g] + b_hh1[g];
    float a0 = bias, a1 = bias, a2 = bias, a3 = bias;
    #pragma unroll 8
    for (int jj = 0; jj < 64; ++jj) {
        float4 w = wrow[jj];
        a0 += dot4(w, xs[0][jj]);
        a1 += dot4(w, xs[1][jj]);
        a2 += dot4(w, xs[2][jj]);
        a3 += dot4(w, xs[3][jj]);
    }
    const int b  = t0 >> 9;          // batch
    const int s0 = t0 & 511;         // first step of the 4
    const int w  = g >> 4;
    const int lane = ((b >> 2) << 4) + (g & 15);
    const int r  = b & 3;
    float vals[4] = {a0, a1, a2, a3};
    #pragma unroll
    for (int k = 0; k < 4; ++k) {
        G1d[(((long)(s0 + k) * 8 + w) * 64 + lane) * 4 + r] = vals[k];
    }
}

// ---------------------------------------------------------------------------
// Kernel B: MFMA-based 2-layer LSTM, all 16 chains in ONE 512-thread block.
// Wave w owns gate columns 16w..16w+15 (i:w0-1, f:w2-3, g:w4-5, o:w6-7).
// Per step: layer1 = 3 MFMA (split-bf16), acts, LDS exchange, cell update;
// layer2 = 6 MFMA (K=64: [h1|h2]). h state kept as bf16 hi/lo in LDS in
// A-fragment layout. Weights live in 6 bf16x8 B-fragments (24 VGPRs).
// ---------------------------------------------------------------------------
__global__ __launch_bounds__(512) void k_lstm_mfma(
    const float* __restrict__ G1d,
    const float* __restrict__ W_hh1,
    const float* __restrict__ W_ih2, const float* __restrict__ W_hh2,
    const float* __restrict__ b_ih2, const float* __restrict__ b_hh2,
    bf16* __restrict__ Hhi, bf16* __restrict__ Hlo)
{
    __shared__ bf16 A2hi[16][72];    // [batch][k]: k 0-31 = h1, 32-63 = h2, pad
    __shared__ bf16 A2lo[16][72];
    __shared__ float act[16][132];   // [batch][gate col] (reused both layers)

    const int t  = threadIdx.x;
    const int w  = t >> 6;           // wave id = N-tile
    const int l  = t & 63;
    const int lr = l & 15, lq = l >> 4;
    const int col = w * 16 + lr;     // gate column this lane owns
    const int u  = t & 31;           // cell unit
    const int bb = t >> 5;           // cell batch

    // --- build B-fragments (hi/lo split) from f32 weights, once ---
    bf16x8 b1h, b1l, bi2h, bi2l, bh2h, bh2l;
    #pragma unroll
    for (int j = 0; j < 8; ++j) {
        float v1 = W_hh1[col * D_H + lq * 8 + j];
        float v2 = W_ih2[col * D_H + lq * 8 + j];
        float v3 = W_hh2[col * D_H + lq * 8 + j];
        bf16 h1b = (bf16)v1, h2b = (bf16)v2, h3b = (bf16)v3;
        b1h[j]  = h1b; b1l[j]  = (bf16)(v1 - (float)h1b);
        bi2h[j] = h2b; bi2l[j] = (bf16)(v2 - (float)h2b);
        bh2h[j] = h3b; bh2l[j] = (bf16)(v3 - (float)h3b);
    }
    const float bias2 = b_ih2[col] + b_hh2[col];
    const bool isTanh = (w == 4 || w == 5);   // 'g' gate columns

    // zero h state
    for (int i = t; i < 16 * 72; i += 512) {
        ((bf16*)A2hi)[i] = (bf16)0.0f;
        ((bf16*)A2lo)[i] = (bf16)0.0f;
    }
    float c1 = 0.0f, c2 = 0.0f;
    __syncthreads();

    const f32x4* G1v = (const f32x4*)G1d;
    f32x4 g1c = G1v[(long)(0 * 8 + w) * 64 + l];

    #pragma unroll 1
    for (int s = 0; s < S_LEN; ++s) {
        // prefetch next step's input gates (1-step slack hides HBM latency)
        const int sn = (s + 1 < S_LEN) ? s + 1 : S_LEN - 1;
        f32x4 g1n = G1v[((long)sn * 8 + w) * 64 + l];

        // ---- layer 1: gates = h1 . W_hh1^T + G1 ----
        bf16x8 a1h = *(const bf16x8*)&A2hi[lr][lq * 8];
        bf16x8 a1l = *(const bf16x8*)&A2lo[lr][lq * 8];
        f32x4 d = __builtin_amdgcn_mfma_f32_16x16x32_bf16(a1h, b1h, g1c, 0, 0, 0);
        d = __builtin_amdgcn_mfma_f32_16x16x32_bf16(a1l, b1h, d, 0, 0, 0);
        d = __builtin_amdgcn_mfma_f32_16x16x32_bf16(a1h, b1l, d, 0, 0, 0);
        #pragma unroll
        for (int r = 0; r < 4; ++r) {
            float a = isTanh ? tanhfast(d[r]) : sigf(d[r]);
            act[lq * 4 + r][col] = a;
        }
        __syncthreads();

        // ---- layer-1 cell update: thread owns (bb, u) ----
        {
            float iv = act[bb][u], fv = act[bb][32 + u];
            float gv = act[bb][64 + u], ov = act[bb][96 + u];
            c1 = fv * c1 + iv * gv;
            float h1 = ov * tanhfast(c1);
            bf16 hh = (bf16)h1;
            A2hi[bb][u] = hh;
            A2lo[bb][u] = (bf16)(h1 - (float)hh);
        }
        __syncthreads();

        // ---- layer 2: gates = [h1|h2] . [W_ih2|W_hh2]^T + bias2 ----
        bf16x8 a2h0 = *(const bf16x8*)&A2hi[lr][lq * 8];
        bf16x8 a2l0 = *(const bf16x8*)&A2lo[lr][lq * 8];
        bf16x8 a2h1 = *(const bf16x8*)&A2hi[lr][32 + lq * 8];
        bf16x8 a2l1 = *(const bf16x8*)&A2lo[lr][32 + lq * 8];
        f32x4 d2 = {bias2, bias2, bias2, bias2};
        d2 = __builtin_amdgcn_mfma_f32_16x16x32_bf16(a2h0, bi2h, d2, 0, 0, 0);
        d2 = __builtin_amdgcn_mfma_f32_16x16x32_bf16(a2l0, bi2h, d2, 0, 0, 0);
        d2 = __builtin_amdgcn_mfma_f32_16x16x32_bf16(a2h0, bi2l, d2, 0, 0, 0);
        d2 = __builtin_amdgcn_mfma_f32_16x16x32_bf16(a2h1, bh2h, d2, 0, 0, 0);
        d2 = __builtin_amdgcn_mfma_f32_16x16x32_bf16(a2l1, bh2h, d2, 0, 0, 0);
        d2 = __builtin_amdgcn_mfma_f32_16x16x32_bf16(a2h1, bh2l, d2, 0, 0, 0);
        #pragma unroll
        for (int r = 0; r < 4; ++r) {
            float a = isTanh ? tanhfast(d2[r]) : sigf(d2[r]);
            act[lq * 4 + r][col] = a;
        }
        __syncthreads();

        // ---- layer-2 cell update + h2 publish ----
        {
            float iv = act[bb][u], fv = act[bb][32 + u];
            float gv = act[bb][64 + u], ov = act[bb][96 + u];
            c2 = fv * c2 + iv * gv;
            float h2 = ov * tanhfast(c2);
            bf16 hh = (bf16)h2;
            bf16 hl = (bf16)(h2 - (float)hh);
            A2hi[bb][32 + u] = hh;
            A2lo[bb][32 + u] = hl;
            const long idx = ((long)bb * S_LEN + s) * D_H + u;
            Hhi[idx] = hh;
            Hlo[idx] = hl;
        }
        __syncthreads();

        g1c = g1n;
    }
}

// ---------------------------------------------------------------------------
// Kernel C1 (MFMA): partial softmax denominators.
// ---------------------------------------------------------------------------
__global__ __launch_bounds__(256) void k_fc_sum(
    const bf16* __restrict__ Hhi, const bf16* __restrict__ Hlo,
    const bf16* __restrict__ Whi, const bf16* __restrict__ Wlo,
    const float* __restrict__ b_fc, float* __restrict__ partial)
{
    const int lane = threadIdx.x & 63;
    const int wid  = threadIdx.x >> 6;
    const int tg   = blockIdx.x / NV1;
    const int nv   = blockIdx.x % NV1;
    const int t0   = tg * 128 + wid * 32;
    const int lr   = lane & 15, lq = lane >> 4;

    const long arow0 = (long)(t0 + lr) * D_H + lq * 8;
    const long arow1 = arow0 + 16 * D_H;
    bf16x8 a0h = *(const bf16x8*)(Hhi + arow0);
    bf16x8 a0l = *(const bf16x8*)(Hlo + arow0);
    bf16x8 a1h = *(const bf16x8*)(Hhi + arow1);
    bf16x8 a1l = *(const bf16x8*)(Hlo + arow1);

    f32x4 acc0 = {0.f, 0.f, 0.f, 0.f}, acc1 = {0.f, 0.f, 0.f, 0.f};
    const f32x4 z = {0.f, 0.f, 0.f, 0.f};
    int v0 = nv * (VOCAB / NV1);
    for (int tile = 0; tile < VT1; ++tile, v0 += 16) {
        const long brow = (long)(v0 + lr) * D_H + lq * 8;
        bf16x8 bh = *(const bf16x8*)(Whi + brow);
        bf16x8 bl = *(const bf16x8*)(Wlo + brow);
        float bias = b_fc[v0 + lr];
        f32x4 d0 = __builtin_amdgcn_mfma_f32_16x16x32_bf16(a0h, bh, z, 0, 0, 0);
        d0 = __builtin_amdgcn_mfma_f32_16x16x32_bf16(a0l, bh, d0, 0, 0, 0);
        d0 = __builtin_amdgcn_mfma_f32_16x16x32_bf16(a0h, bl, d0, 0, 0, 0);
        f32x4 d1 = __builtin_amdgcn_mfma_f32_16x16x32_bf16(a1h, bh, z, 0, 0, 0);
        d1 = __builtin_amdgcn_mfma_f32_16x16x32_bf16(a1l, bh, d1, 0, 0, 0);
        d1 = __builtin_amdgcn_mfma_f32_16x16x32_bf16(a1h, bl, d1, 0, 0, 0);
        #pragma unroll
        for (int r = 0; r < 4; ++r) {
            acc0[r] += __expf(d0[r] + bias);
            acc1[r] += __expf(d1[r] + bias);
        }
    }

    #pragma unroll
    for (int m = 1; m < 16; m <<= 1) {
        #pragma unroll
        for (int r = 0; r < 4; ++r) {
            acc0[r] += __shfl_xor(acc0[r], m, 64);
            acc1[r] += __shfl_xor(acc1[r], m, 64);
        }
    }
    if (lr == 0) {
        #pragma unroll
        for (int r = 0; r < 4; ++r) {
            partial[(long)nv * NTOK + t0 + lq * 4 + r]      = acc0[r];
            partial[(long)nv * NTOK + t0 + 16 + lq * 4 + r] = acc1[r];
        }
    }
}

__global__ __launch_bounds__(256) void k_inv(
    const float* __restrict__ partial, float* __restrict__ inv_sum)
{
    const int t = blockIdx.x * 256 + threadIdx.x;
    float s = 0.0f;
    #pragma unroll
    for (int nv = 0; nv < NV1; ++nv) s += partial[(long)nv * NTOK + t];
    inv_sum[t] = 1.0f / s;
}

// ---------------------------------------------------------------------------
// Kernel C2 (MFMA): recompute logits, write normalized softmax.
// ---------------------------------------------------------------------------
__global__ __launch_bounds__(256) void k_fc_out(
    const bf16* __restrict__ Hhi, const bf16* __restrict__ Hlo,
    const bf16* __restrict__ Whi, const bf16* __restrict__ Wlo,
    const float* __restrict__ b_fc, const float* __restrict__ inv_sum,
    float* __restrict__ out)
{
    const int lane = threadIdx.x & 63;
    const int wid  = threadIdx.x >> 6;
    const int tg   = blockIdx.x / NV2;
    const int nv   = blockIdx.x % NV2;
    const int t0   = tg * 128 + wid * 32;
    const int lr   = lane & 15, lq = lane >> 4;

    const long arow0 = (long)(t0 + lr) * D_H + lq * 8;
    const long arow1 = arow0 + 16 * D_H;
    bf16x8 a0h = *(const bf16x8*)(Hhi + arow0);
    bf16x8 a0l = *(const bf16x8*)(Hlo + arow0);
    bf16x8 a1h = *(const bf16x8*)(Hhi + arow1);
    bf16x8 a1l = *(const bf16x8*)(Hlo + arow1);

    float inv0[4], inv1[4];
    #pragma unroll
    for (int r = 0; r < 4; ++r) {
        inv0[r] = inv_sum[t0 + lq * 4 + r];
        inv1[r] = inv_sum[t0 + 16 + lq * 4 + r];
    }

    const f32x4 z = {0.f, 0.f, 0.f, 0.f};
    int v0 = nv * (VOCAB / NV2);
    for (int tile = 0; tile < VT2; ++tile, v0 += 16) {
        const long brow = (long)(v0 + lr) * D_H + lq * 8;
        bf16x8 bh = *(const bf16x8*)(Whi + brow);
        bf16x8 bl = *(const bf16x8*)(Wlo + brow);
        float bias = b_fc[v0 + lr];
        f32x4 d0 = __builtin_amdgcn_mfma_f32_16x16x32_bf16(a0h, bh, z, 0, 0, 0);
        d0 = __builtin_amdgcn_mfma_f32_16x16x32_bf16(a0l, bh, d0, 0, 0, 0);
        d0 = __builtin_amdgcn_mfma_f32_16x16x32_bf16(a0h, bl, d0, 0, 0, 0);
        f32x4 d1 = __builtin_amdgcn_mfma_f32_16x16x32_bf16(a1h, bh, z, 0, 0, 0);
        d1 = __builtin_amdgcn_mfma_f32_16x16x32_bf16(a1l, bh, d1, 0, 0, 0);
        d1 = __builtin_amdgcn_mfma_f32_16x16x32_bf16(a1h, bl, d1, 0, 0, 0);
        const int vcol = v0 + lr;
        #pragma unroll
        for (int r = 0; r < 4; ++r) {
            out[(long)(t0 + lq * 4 + r) * VOCAB + vcol] =
                __expf(d0[r] + bias) * inv0[r];
            out[(long)(t0 + 16 + lq * 4 + r) * VOCAB + vcol] =
                __expf(d1[r] + bias) * inv1[r];
        }
    }
}

// ---------------------------------------------------------------------------
extern "C" void kernel_launch(void* const* d_in, const int* in_sizes, int n_in,
                              void* d_out, int out_size, void* d_ws, size_t ws_size,
                              hipStream_t stream)
{
    const int*   x_ids = (const int*)d_in[0];
    const float* emb   = (const float*)d_in[1];
    const float* W_ih1 = (const float*)d_in[2];
    const float* W_hh1 = (const float*)d_in[3];
    const float* b_ih1 = (const float*)d_in[4];
    const float* b_hh1 = (const float*)d_in[5];
    const float* W_ih2 = (const float*)d_in[6];
    const float* W_hh2 = (const float*)d_in[7];
    const float* b_ih2 = (const float*)d_in[8];
    const float* b_hh2 = (const float*)d_in[9];
    const float* W_fc  = (const float*)d_in[10];
    const float* b_fc  = (const float*)d_in[11];
    float* out = (float*)d_out;

    char* p = (char*)d_ws;
    float* G1d     = (float*)p;            p += (long)S_LEN * 8 * 64 * 4 * 4; // 4 MB
    bf16* Hhi      = (bf16*)p;             p += (long)NTOK * D_H * 2;   // 512 KB
    bf16* Hlo      = (bf16*)p;             p += (long)NTOK * D_H * 2;   // 512 KB
    bf16* Whi      = (bf16*)p;             p += (long)VOCAB * D_H * 2;  // 2 MB
    bf16* Wlo      = (bf16*)p;             p += (long)VOCAB * D_H * 2;  // 2 MB
    float* partial = (float*)p;            p += (long)NV1 * NTOK * 4;   // 512 KB
    float* inv_sum = (float*)p;            p += (long)NTOK * 4;         // 32 KB

    k_cvt_w<<<VOCAB * D_H / (256 * 4), 256, 0, stream>>>(W_fc, Whi, Wlo);
    k_embed_gates<<<NTOK / 4, 128, 0, stream>>>(x_ids, emb, W_ih1, b_ih1, b_hh1, G1d);
    k_lstm_mfma<<<1, 512, 0, stream>>>(G1d, W_hh1, W_ih2, W_hh2, b_ih2, b_hh2, Hhi, Hlo);
    k_fc_sum<<<(NTOK / 128) * NV1, 256, 0, stream>>>(Hhi, Hlo, Whi, Wlo, b_fc, partial);
    k_inv<<<NTOK / 256, 256, 0, stream>>>(partial, inv_sum);
    k_fc_out<<<(NTOK / 128) * NV2, 256, 0, stream>>>(Hhi, Hlo, Whi, Wlo, b_fc, inv_sum, out);
}

// Round 14
// 841.489 us; speedup vs baseline: 374.6784x; 1.2478x over previous
//
#include <hip/hip_runtime.h>
#include <math.h>

#define VOCAB 32000
#define D_IN  256
#define D_H   32
#define B_SZ  16
#define S_LEN 512
#define NTOK  (B_SZ * S_LEN)   // 8192
#define NV1   16               // vocab splits in sum pass
#define VT1   (VOCAB / 16 / NV1)   // 125 tiles of 16 rows
#define NV2   25               // vocab splits in out pass
#define VT2   (VOCAB / 16 / NV2)   // 80 tiles

typedef __bf16 bf16;
typedef __attribute__((ext_vector_type(8))) __bf16 bf16x8;
typedef __attribute__((ext_vector_type(4))) __bf16 bf16x4;
typedef __attribute__((ext_vector_type(4))) float f32x4;

__device__ __forceinline__ float sigf(float x) {
    return 1.0f / (1.0f + __expf(-x));
}

__device__ __forceinline__ float tanhfast(float x) {
    float ax = fabsf(x);
    float e = __expf(-2.0f * ax);
    float r = (1.0f - e) / (1.0f + e);
    return copysignf(r, x);
}

__device__ __forceinline__ float dot4(float4 a, float4 b) {
    return a.x * b.x + a.y * b.y + a.z * b.z + a.w * b.w;
}

// ---------------------------------------------------------------------------
// Convert W_fc (f32 [32000][32]) to bf16 hi/lo split arrays.
// ---------------------------------------------------------------------------
__global__ __launch_bounds__(256) void k_cvt_w(
    const float* __restrict__ W, bf16* __restrict__ Whi, bf16* __restrict__ Wlo)
{
    const long i = ((long)blockIdx.x * 256 + threadIdx.x) * 4;
    float4 w = *(const float4*)(W + i);
    bf16 h0 = (bf16)w.x, h1 = (bf16)w.y, h2 = (bf16)w.z, h3 = (bf16)w.w;
    bf16 l0 = (bf16)(w.x - (float)h0), l1 = (bf16)(w.y - (float)h1);
    bf16 l2 = (bf16)(w.z - (float)h2), l3 = (bf16)(w.w - (float)h3);
    bf16x4 hv = {h0, h1, h2, h3}, lv = {l0, l1, l2, l3};
    *(bf16x4*)(Whi + i) = hv;
    *(bf16x4*)(Wlo + i) = lv;
}

// ---------------------------------------------------------------------------
// Kernel A: input-side gates packed into the LSTM's D/C-fragment order:
// M-rows = gates-of-units (m = u_local*4 + gate), N = batch.
// float index (((s*8 + w)*64 + lane)*4 + r) with lane = lq*16 + b holds
// G1[b][s][g = r*32 + 4w + lq].
// ---------------------------------------------------------------------------
__global__ __launch_bounds__(128) void k_embed_gates(
    const int* __restrict__ x_ids, const float* __restrict__ emb,
    const float* __restrict__ W_ih1, const float* __restrict__ b_ih1,
    const float* __restrict__ b_hh1, float* __restrict__ G1d)
{
    __shared__ float4 xs[4][64];
    const int tid = threadIdx.x;
    const int t0  = blockIdx.x * 4;          // 4 consecutive tokens, same batch
    const int r0  = tid >> 6, j = tid & 63;
    #pragma unroll
    for (int rr = 0; rr < 2; ++rr) {
        int r = rr * 2 + r0;
        long id = x_ids[t0 + r];
        xs[r][j] = ((const float4*)(emb + id * (long)D_IN))[j];
    }
    __syncthreads();

    const int g = tid;
    const float4* wrow = (const float4*)(W_ih1 + (long)g * D_IN);
    const float bias = b_ih1[g] + b_hh1[g];
    float a0 = bias, a1 = bias, a2 = bias, a3 = bias;
    #pragma unroll 8
    for (int jj = 0; jj < 64; ++jj) {
        float4 w = wrow[jj];
        a0 += dot4(w, xs[0][jj]);
        a1 += dot4(w, xs[1][jj]);
        a2 += dot4(w, xs[2][jj]);
        a3 += dot4(w, xs[3][jj]);
    }
    const int b  = t0 >> 9;          // batch
    const int s0 = t0 & 511;         // first step
    const int gt = g >> 5;           // gate type (i,f,g,o)
    const int u  = g & 31;           // unit
    const int w  = u >> 2;           // wave owning this unit
    const int lq = u & 3;
    const int lane = lq * 16 + b;
    float vals[4] = {a0, a1, a2, a3};
    #pragma unroll
    for (int k = 0; k < 4; ++k) {
        G1d[(((long)(s0 + k) * 8 + w) * 64 + lane) * 4 + gt] = vals[k];
    }
}

// ---------------------------------------------------------------------------
// Kernel B: MFMA LSTM v2 — lane-local cell update, 2 barriers/step.
// A = static weight fragments (VGPRs), B = h fragments, M-rows = 4 gates x
// 4 units per wave, N = 16 batches. Lane (lq,lr) owns all 4 gates of
// (unit 4w+lq, batch lr). h exchanged via double-buffered LDS.
// ---------------------------------------------------------------------------
__global__ __launch_bounds__(512, 1) void k_lstm_mfma(
    const float* __restrict__ G1d,
    const float* __restrict__ W_hh1,
    const float* __restrict__ W_ih2, const float* __restrict__ W_hh2,
    const float* __restrict__ b_ih2, const float* __restrict__ b_hh2,
    bf16* __restrict__ Hhi, bf16* __restrict__ Hlo)
{
    __shared__ alignas(16) bf16 H1h[2][16][40], H1l[2][16][40];
    __shared__ alignas(16) bf16 H2h[2][16][40], H2l[2][16][40];

    const int t  = threadIdx.x;
    const int w  = t >> 6;
    const int l  = t & 63;
    const int lr = l & 15, lq = l >> 4;

    // A-fragment: lane's A row m = lr -> W row g = (lr&3)*32 + 4w + (lr>>2)
    const int garow = (lr & 3) * 32 + 4 * w + (lr >> 2);
    bf16x8 w1h, w1l, wi2h, wi2l, wh2h, wh2l;
    #pragma unroll
    for (int j = 0; j < 8; ++j) {
        float v1 = W_hh1[garow * D_H + lq * 8 + j];
        float v2 = W_ih2[garow * D_H + lq * 8 + j];
        float v3 = W_hh2[garow * D_H + lq * 8 + j];
        bf16 b1 = (bf16)v1, b2 = (bf16)v2, b3 = (bf16)v3;
        w1h[j]  = b1; w1l[j]  = (bf16)(v1 - (float)b1);
        wi2h[j] = b2; wi2l[j] = (bf16)(v2 - (float)b2);
        wh2h[j] = b3; wh2l[j] = (bf16)(v3 - (float)b3);
    }

    // this lane's cell: unit u = 4w + lq, batch lr; D rows m=4lq+r -> gate r
    const int u = 4 * w + lq;
    f32x4 bias2;
    #pragma unroll
    for (int r = 0; r < 4; ++r)
        bias2[r] = b_ih2[r * 32 + u] + b_hh2[r * 32 + u];

    bf16x8 h1fh, h1fl, h2fh, h2fl;
    #pragma unroll
    for (int j = 0; j < 8; ++j) {
        h1fh[j] = (bf16)0.0f; h1fl[j] = (bf16)0.0f;
        h2fh[j] = (bf16)0.0f; h2fl[j] = (bf16)0.0f;
    }
    float c1 = 0.0f, c2 = 0.0f;

    const f32x4* G1v = (const f32x4*)G1d;
    f32x4 g1c = G1v[(long)w * 64 + l];

    #pragma unroll 2
    for (int s = 0; s < S_LEN; ++s) {
        const int p  = s & 1;
        const int sn = (s + 1 < S_LEN) ? s + 1 : s;
        f32x4 g1n = G1v[((long)sn * 8 + w) * 64 + l];

        // ---- layer 1: D = W1 . h1(t-1) + G1 ----
        f32x4 d = __builtin_amdgcn_mfma_f32_16x16x32_bf16(w1h, h1fh, g1c, 0, 0, 0);
        d = __builtin_amdgcn_mfma_f32_16x16x32_bf16(w1l, h1fh, d, 0, 0, 0);
        d = __builtin_amdgcn_mfma_f32_16x16x32_bf16(w1h, h1fl, d, 0, 0, 0);
        float iv = sigf(d[0]), fv = sigf(d[1]);
        float gv = tanhfast(d[2]), ov = sigf(d[3]);
        c1 = fv * c1 + iv * gv;
        float h1 = ov * tanhfast(c1);
        bf16 hh = (bf16)h1;
        H1h[p][lr][u] = hh;
        H1l[p][lr][u] = (bf16)(h1 - (float)hh);
        __syncthreads();
        h1fh = *(const bf16x8*)&H1h[p][lr][lq * 8];
        h1fl = *(const bf16x8*)&H1l[p][lr][lq * 8];

        // ---- layer 2: D = Wih2 . h1(t) + Whh2 . h2(t-1) + bias2 ----
        f32x4 d2 = bias2;
        d2 = __builtin_amdgcn_mfma_f32_16x16x32_bf16(wi2h, h1fh, d2, 0, 0, 0);
        d2 = __builtin_amdgcn_mfma_f32_16x16x32_bf16(wi2l, h1fh, d2, 0, 0, 0);
        d2 = __builtin_amdgcn_mfma_f32_16x16x32_bf16(wi2h, h1fl, d2, 0, 0, 0);
        d2 = __builtin_amdgcn_mfma_f32_16x16x32_bf16(wh2h, h2fh, d2, 0, 0, 0);
        d2 = __builtin_amdgcn_mfma_f32_16x16x32_bf16(wh2l, h2fh, d2, 0, 0, 0);
        d2 = __builtin_amdgcn_mfma_f32_16x16x32_bf16(wh2h, h2fl, d2, 0, 0, 0);
        iv = sigf(d2[0]); fv = sigf(d2[1]);
        gv = tanhfast(d2[2]); ov = sigf(d2[3]);
        c2 = fv * c2 + iv * gv;
        float h2 = ov * tanhfast(c2);
        hh = (bf16)h2;
        H2h[p][lr][u] = hh;
        H2l[p][lr][u] = (bf16)(h2 - (float)hh);
        __syncthreads();
        h2fh = *(const bf16x8*)&H2h[p][lr][lq * 8];
        h2fl = *(const bf16x8*)&H2l[p][lr][lq * 8];

        if (w == 0) {   // B-fragment is wave-replicated: one wave stores
            const long base = ((long)lr * S_LEN + s) * D_H + lq * 8;
            *(bf16x8*)(Hhi + base) = h2fh;
            *(bf16x8*)(Hlo + base) = h2fl;
        }
        g1c = g1n;
    }
}

// ---------------------------------------------------------------------------
// Kernel C1 (MFMA): partial softmax denominators.
// ---------------------------------------------------------------------------
__global__ __launch_bounds__(256) void k_fc_sum(
    const bf16* __restrict__ Hhi, const bf16* __restrict__ Hlo,
    const bf16* __restrict__ Whi, const bf16* __restrict__ Wlo,
    const float* __restrict__ b_fc, float* __restrict__ partial)
{
    const int lane = threadIdx.x & 63;
    const int wid  = threadIdx.x >> 6;
    const int tg   = blockIdx.x / NV1;
    const int nv   = blockIdx.x % NV1;
    const int t0   = tg * 128 + wid * 32;
    const int lr   = lane & 15, lq = lane >> 4;

    const long arow0 = (long)(t0 + lr) * D_H + lq * 8;
    const long arow1 = arow0 + 16 * D_H;
    bf16x8 a0h = *(const bf16x8*)(Hhi + arow0);
    bf16x8 a0l = *(const bf16x8*)(Hlo + arow0);
    bf16x8 a1h = *(const bf16x8*)(Hhi + arow1);
    bf16x8 a1l = *(const bf16x8*)(Hlo + arow1);

    f32x4 acc0 = {0.f, 0.f, 0.f, 0.f}, acc1 = {0.f, 0.f, 0.f, 0.f};
    const f32x4 z = {0.f, 0.f, 0.f, 0.f};
    int v0 = nv * (VOCAB / NV1);
    for (int tile = 0; tile < VT1; ++tile, v0 += 16) {
        const long brow = (long)(v0 + lr) * D_H + lq * 8;
        bf16x8 bh = *(const bf16x8*)(Whi + brow);
        bf16x8 bl = *(const bf16x8*)(Wlo + brow);
        float bias = b_fc[v0 + lr];
        f32x4 d0 = __builtin_amdgcn_mfma_f32_16x16x32_bf16(a0h, bh, z, 0, 0, 0);
        d0 = __builtin_amdgcn_mfma_f32_16x16x32_bf16(a0l, bh, d0, 0, 0, 0);
        d0 = __builtin_amdgcn_mfma_f32_16x16x32_bf16(a0h, bl, d0, 0, 0, 0);
        f32x4 d1 = __builtin_amdgcn_mfma_f32_16x16x32_bf16(a1h, bh, z, 0, 0, 0);
        d1 = __builtin_amdgcn_mfma_f32_16x16x32_bf16(a1l, bh, d1, 0, 0, 0);
        d1 = __builtin_amdgcn_mfma_f32_16x16x32_bf16(a1h, bl, d1, 0, 0, 0);
        #pragma unroll
        for (int r = 0; r < 4; ++r) {
            acc0[r] += __expf(d0[r] + bias);
            acc1[r] += __expf(d1[r] + bias);
        }
    }

    #pragma unroll
    for (int m = 1; m < 16; m <<= 1) {
        #pragma unroll
        for (int r = 0; r < 4; ++r) {
            acc0[r] += __shfl_xor(acc0[r], m, 64);
            acc1[r] += __shfl_xor(acc1[r], m, 64);
        }
    }
    if (lr == 0) {
        #pragma unroll
        for (int r = 0; r < 4; ++r) {
            partial[(long)nv * NTOK + t0 + lq * 4 + r]      = acc0[r];
            partial[(long)nv * NTOK + t0 + 16 + lq * 4 + r] = acc1[r];
        }
    }
}

__global__ __launch_bounds__(256) void k_inv(
    const float* __restrict__ partial, float* __restrict__ inv_sum)
{
    const int t = blockIdx.x * 256 + threadIdx.x;
    float s = 0.0f;
    #pragma unroll
    for (int nv = 0; nv < NV1; ++nv) s += partial[(long)nv * NTOK + t];
    inv_sum[t] = 1.0f / s;
}

// ---------------------------------------------------------------------------
// Kernel C2 (MFMA): recompute logits, write normalized softmax.
// ---------------------------------------------------------------------------
__global__ __launch_bounds__(256) void k_fc_out(
    const bf16* __restrict__ Hhi, const bf16* __restrict__ Hlo,
    const bf16* __restrict__ Whi, const bf16* __restrict__ Wlo,
    const float* __restrict__ b_fc, const float* __restrict__ inv_sum,
    float* __restrict__ out)
{
    const int lane = threadIdx.x & 63;
    const int wid  = threadIdx.x >> 6;
    const int tg   = blockIdx.x / NV2;
    const int nv   = blockIdx.x % NV2;
    const int t0   = tg * 128 + wid * 32;
    const int lr   = lane & 15, lq = lane >> 4;

    const long arow0 = (long)(t0 + lr) * D_H + lq * 8;
    const long arow1 = arow0 + 16 * D_H;
    bf16x8 a0h = *(const bf16x8*)(Hhi + arow0);
    bf16x8 a0l = *(const bf16x8*)(Hlo + arow0);
    bf16x8 a1h = *(const bf16x8*)(Hhi + arow1);
    bf16x8 a1l = *(const bf16x8*)(Hlo + arow1);

    float inv0[4], inv1[4];
    #pragma unroll
    for (int r = 0; r < 4; ++r) {
        inv0[r] = inv_sum[t0 + lq * 4 + r];
        inv1[r] = inv_sum[t0 + 16 + lq * 4 + r];
    }

    const f32x4 z = {0.f, 0.f, 0.f, 0.f};
    int v0 = nv * (VOCAB / NV2);
    for (int tile = 0; tile < VT2; ++tile, v0 += 16) {
        const long brow = (long)(v0 + lr) * D_H + lq * 8;
        bf16x8 bh = *(const bf16x8*)(Whi + brow);
        bf16x8 bl = *(const bf16x8*)(Wlo + brow);
        float bias = b_fc[v0 + lr];
        f32x4 d0 = __builtin_amdgcn_mfma_f32_16x16x32_bf16(a0h, bh, z, 0, 0, 0);
        d0 = __builtin_amdgcn_mfma_f32_16x16x32_bf16(a0l, bh, d0, 0, 0, 0);
        d0 = __builtin_amdgcn_mfma_f32_16x16x32_bf16(a0h, bl, d0, 0, 0, 0);
        f32x4 d1 = __builtin_amdgcn_mfma_f32_16x16x32_bf16(a1h, bh, z, 0, 0, 0);
        d1 = __builtin_amdgcn_mfma_f32_16x16x32_bf16(a1l, bh, d1, 0, 0, 0);
        d1 = __builtin_amdgcn_mfma_f32_16x16x32_bf16(a1h, bl, d1, 0, 0, 0);
        const int vcol = v0 + lr;
        #pragma unroll
        for (int r = 0; r < 4; ++r) {
            out[(long)(t0 + lq * 4 + r) * VOCAB + vcol] =
                __expf(d0[r] + bias) * inv0[r];
            out[(long)(t0 + 16 + lq * 4 + r) * VOCAB + vcol] =
                __expf(d1[r] + bias) * inv1[r];
        }
    }
}

// ---------------------------------------------------------------------------
extern "C" void kernel_launch(void* const* d_in, const int* in_sizes, int n_in,
                              void* d_out, int out_size, void* d_ws, size_t ws_size,
                              hipStream_t stream)
{
    const int*   x_ids = (const int*)d_in[0];
    const float* emb   = (const float*)d_in[1];
    const float* W_ih1 = (const float*)d_in[2];
    const float* W_hh1 = (const float*)d_in[3];
    const float* b_ih1 = (const float*)d_in[4];
    const float* b_hh1 = (const float*)d_in[5];
    const float* W_ih2 = (const float*)d_in[6];
    const float* W_hh2 = (const float*)d_in[7];
    const float* b_ih2 = (const float*)d_in[8];
    const float* b_hh2 = (const float*)d_in[9];
    const float* W_fc  = (const float*)d_in[10];
    const float* b_fc  = (const float*)d_in[11];
    float* out = (float*)d_out;

    char* p = (char*)d_ws;
    float* G1d     = (float*)p;            p += (long)S_LEN * 8 * 64 * 4 * 4; // 4 MB
    bf16* Hhi      = (bf16*)p;             p += (long)NTOK * D_H * 2;   // 512 KB
    bf16* Hlo      = (bf16*)p;             p += (long)NTOK * D_H * 2;   // 512 KB
    bf16* Whi      = (bf16*)p;             p += (long)VOCAB * D_H * 2;  // 2 MB
    bf16* Wlo      = (bf16*)p;             p += (long)VOCAB * D_H * 2;  // 2 MB
    float* partial = (float*)p;            p += (long)NV1 * NTOK * 4;   // 512 KB
    float* inv_sum = (float*)p;            p += (long)NTOK * 4;         // 32 KB

    k_cvt_w<<<VOCAB * D_H / (256 * 4), 256, 0, stream>>>(W_fc, Whi, Wlo);
    k_embed_gates<<<NTOK / 4, 128, 0, stream>>>(x_ids, emb, W_ih1, b_ih1, b_hh1, G1d);
    k_lstm_mfma<<<1, 512, 0, stream>>>(G1d, W_hh1, W_ih2, W_hh2, b_ih2, b_hh2, Hhi, Hlo);
    k_fc_sum<<<(NTOK / 128) * NV1, 256, 0, stream>>>(Hhi, Hlo, Whi, Wlo, b_fc, partial);
    k_inv<<<NTOK / 256, 256, 0, stream>>>(partial, inv_sum);
    k_fc_out<<<(NTOK / 128) * NV2, 256, 0, stream>>>(Hhi, Hlo, Whi, Wlo, b_fc, inv_sum, out);
}